// Round 3
// baseline (782.205 us; speedup 1.0000x reference)
//
#include <hip/hip_runtime.h>

typedef __bf16 bf16;
typedef __bf16 bf16x4 __attribute__((ext_vector_type(4)));
typedef __bf16 bf16x8 __attribute__((ext_vector_type(8)));
typedef float  f32x4  __attribute__((ext_vector_type(4)));

// ---------------------------------------------------------------------------
// Split fp32 -> bf16 hi + bf16 lo  (v = hi + lo exactly to ~2^-18 rel)
// ---------------------------------------------------------------------------
__global__ __launch_bounds__(256) void split_f32(const float* __restrict__ in,
                                                 bf16* __restrict__ hi,
                                                 bf16* __restrict__ lo, long n4) {
  long i = ((long)blockIdx.x * 256 + threadIdx.x) * 4;
  if (i >= n4) return;
  f32x4 v = *(const f32x4*)(in + i);
  bf16x4 h, l;
#pragma unroll
  for (int j = 0; j < 4; j++) {
    bf16 hh = (bf16)v[j];
    h[j] = hh;
    l[j] = (bf16)(v[j] - (float)hh);
  }
  *(bf16x4*)(hi + i) = h;
  *(bf16x4*)(lo + i) = l;
}

// ---------------------------------------------------------------------------
// Transpose + split: float in[R][C] -> bf16 hi[C][R], lo[C][R].  block (32,8)
// ---------------------------------------------------------------------------
__global__ __launch_bounds__(256) void tsplit(const float* __restrict__ in,
                                              bf16* __restrict__ hi,
                                              bf16* __restrict__ lo, int R, int C) {
  __shared__ float tile[32][33];
  int tx = threadIdx.x, ty = threadIdx.y;
  int c = blockIdx.x * 32 + tx;
#pragma unroll
  for (int i = 0; i < 4; i++) {
    int r = blockIdx.y * 32 + ty + i * 8;
    tile[ty + i * 8][tx] = in[(long)r * C + c];
  }
  __syncthreads();
  int c2 = blockIdx.y * 32 + tx;
#pragma unroll
  for (int i = 0; i < 4; i++) {
    int r2 = blockIdx.x * 32 + ty + i * 8;
    float v = tile[tx][ty + i * 8];
    bf16 h = (bf16)v;
    hi[(long)r2 * R + c2] = h;
    lo[(long)r2 * R + c2] = (bf16)(v - (float)h);
  }
}

// ---------------------------------------------------------------------------
// Split-precision GEMM: C[M,N] = (Ah+Al)[M,K] @ (Bh+Bl)[N,K]^T  (fp32 out)
// 64x64 tile, BK=32, 4 waves, 2x2 MFMA 16x16x32, 3 terms: hh + lh + hl.
// A-frag a[j]=A[m=lane&15][k=(lane>>4)*8+j]; C/D col=lane&15,row=(lane>>4)*4+reg.
// ---------------------------------------------------------------------------
template <int BIAS>
__global__ __launch_bounds__(256) void gemm_split(const bf16* __restrict__ Ah_g,
                                                  const bf16* __restrict__ Al_g,
                                                  const bf16* __restrict__ Bh_g,
                                                  const bf16* __restrict__ Bl_g,
                                                  const float* __restrict__ bias,
                                                  float* __restrict__ C,
                                                  int M, int N, int K) {
  __shared__ __align__(16) bf16 Ah[64][40], Al[64][40], Bh[64][40], Bl[64][40];
  int t = threadIdx.x;
  int lane = t & 63, wave = t >> 6;
  int wm = wave >> 1, wn = wave & 1;
  int m0 = blockIdx.y * 64, n0 = blockIdx.x * 64;
  int srow = t >> 2, scol = (t & 3) * 8;
  int q = lane >> 4, r = lane & 15;

  long aoff = (long)(m0 + srow) * K + scol;
  long boff = (long)(n0 + srow) * K + scol;

  f32x4 acc00 = {0.f, 0.f, 0.f, 0.f}, acc01 = acc00, acc10 = acc00, acc11 = acc00;

  for (int k0 = 0; k0 < K; k0 += 32) {
    *(bf16x8*)&Ah[srow][scol] = *(const bf16x8*)(Ah_g + aoff + k0);
    *(bf16x8*)&Al[srow][scol] = *(const bf16x8*)(Al_g + aoff + k0);
    *(bf16x8*)&Bh[srow][scol] = *(const bf16x8*)(Bh_g + boff + k0);
    *(bf16x8*)&Bl[srow][scol] = *(const bf16x8*)(Bl_g + boff + k0);
    __syncthreads();
    bf16x8 a0h = *(const bf16x8*)&Ah[wm * 32 + r][q * 8];
    bf16x8 a1h = *(const bf16x8*)&Ah[wm * 32 + 16 + r][q * 8];
    bf16x8 a0l = *(const bf16x8*)&Al[wm * 32 + r][q * 8];
    bf16x8 a1l = *(const bf16x8*)&Al[wm * 32 + 16 + r][q * 8];
    bf16x8 b0h = *(const bf16x8*)&Bh[wn * 32 + r][q * 8];
    bf16x8 b1h = *(const bf16x8*)&Bh[wn * 32 + 16 + r][q * 8];
    bf16x8 b0l = *(const bf16x8*)&Bl[wn * 32 + r][q * 8];
    bf16x8 b1l = *(const bf16x8*)&Bl[wn * 32 + 16 + r][q * 8];
    acc00 = __builtin_amdgcn_mfma_f32_16x16x32_bf16(a0h, b0h, acc00, 0, 0, 0);
    acc00 = __builtin_amdgcn_mfma_f32_16x16x32_bf16(a0l, b0h, acc00, 0, 0, 0);
    acc00 = __builtin_amdgcn_mfma_f32_16x16x32_bf16(a0h, b0l, acc00, 0, 0, 0);
    acc01 = __builtin_amdgcn_mfma_f32_16x16x32_bf16(a0h, b1h, acc01, 0, 0, 0);
    acc01 = __builtin_amdgcn_mfma_f32_16x16x32_bf16(a0l, b1h, acc01, 0, 0, 0);
    acc01 = __builtin_amdgcn_mfma_f32_16x16x32_bf16(a0h, b1l, acc01, 0, 0, 0);
    acc10 = __builtin_amdgcn_mfma_f32_16x16x32_bf16(a1h, b0h, acc10, 0, 0, 0);
    acc10 = __builtin_amdgcn_mfma_f32_16x16x32_bf16(a1l, b0h, acc10, 0, 0, 0);
    acc10 = __builtin_amdgcn_mfma_f32_16x16x32_bf16(a1h, b0l, acc10, 0, 0, 0);
    acc11 = __builtin_amdgcn_mfma_f32_16x16x32_bf16(a1h, b1h, acc11, 0, 0, 0);
    acc11 = __builtin_amdgcn_mfma_f32_16x16x32_bf16(a1l, b1h, acc11, 0, 0, 0);
    acc11 = __builtin_amdgcn_mfma_f32_16x16x32_bf16(a1h, b1l, acc11, 0, 0, 0);
    __syncthreads();
  }

  int rbase = m0 + wm * 32 + q * 4;
  int cbase = n0 + wn * 32 + r;
  auto emit = [&](f32x4 v, int rb, int col) {
#pragma unroll
    for (int i = 0; i < 4; i++) {
      float val = v[i];
      if (BIAS) val += bias[col];
      C[(long)(rb + i) * N + col] = val;
    }
  };
  emit(acc00, rbase, cbase);
  emit(acc01, rbase, cbase + 16);
  emit(acc10, rbase + 16, cbase);
  emit(acc11, rbase + 16, cbase + 16);
}

// ---------------------------------------------------------------------------
// Fused RMSNorm (inner=1024) + RoPE (per 64-dim head, interleaved pairs),
// IN-PLACE fp32. grid=(4096,2): y==0 -> q rows (stride 1024),
// y==1 -> k half of kv rows (stride 2048, cols 0..1023).
// ---------------------------------------------------------------------------
__global__ __launch_bounds__(256) void normrope_kernel(float* __restrict__ qbuf,
                                                       float* __restrict__ kvbuf,
                                                       const float* __restrict__ wq,
                                                       const float* __restrict__ wk) {
  int row = blockIdx.x;
  int which = blockIdx.y;
  float* ptr = which ? (kvbuf + (long)row * 2048) : (qbuf + (long)row * 1024);
  const float* w = which ? wk : wq;
  int t = threadIdx.x;
  int j0 = t * 4;

  f32x4 xv = *(const f32x4*)(ptr + j0);
  float ss = xv[0] * xv[0] + xv[1] * xv[1] + xv[2] * xv[2] + xv[3] * xv[3];
#pragma unroll
  for (int off = 32; off > 0; off >>= 1) ss += __shfl_down(ss, off);
  __shared__ float red[4];
  if ((t & 63) == 0) red[t >> 6] = ss;
  __syncthreads();
  float total = red[0] + red[1] + red[2] + red[3];
  float scale = rsqrtf(total * (1.0f / 1024.0f) + 1e-6f);

  int n = row & 2047;  // position within sequence (batch stride 2048 rows)
#pragma unroll
  for (int pp = 0; pp < 2; pp++) {
    int j = j0 + 2 * pp;
    int ii = (j & 63) >> 1;  // pair index within head
    // theta = 10000^(-ii/32)
    float theta = __expf((float)ii * (-9.210340371976184f / 32.0f));
    float ang = (float)n * theta;
    float sn, cs;
    __sincosf(ang, &sn, &cs);
    float a0 = xv[2 * pp] * scale * w[j];
    float a1 = xv[2 * pp + 1] * scale * w[j + 1];
    ptr[j] = cs * a0 - sn * a1;
    ptr[j + 1] = sn * a0 + cs * a1;
  }
}

// ---------------------------------------------------------------------------
// Flash attention (VALU fp32, online softmax). One block per (b, h, 64-q tile).
// 256 threads: ty=t>>4 (4 q rows), tx=t&15 (4 k cols / 4 d dims). 4x4 micro-tile.
// Q from qbuf (fp32, stride 1024, roped). K cols 0..1023 / V cols 1024..2047 of
// kvbuf (fp32, stride 2048), K roped in place. LDS 48KB: Pt aliases Kt.
// ---------------------------------------------------------------------------
__global__ __launch_bounds__(256) void attn_kernel(const float* __restrict__ Qb,
                                                   const float* __restrict__ KVb,
                                                   float* __restrict__ Out) {
  __shared__ float Qt[64][64];    // [d][q], pre-scaled by 1/8
  __shared__ float KtPt[64][64];  // phase 1: K^T [d][k]; phase 2: P^T [k][q] swizzled
  __shared__ float Vs[64][64];    // [k][d]

  int t = threadIdx.x;
  int tx = t & 15, ty = t >> 4;
  int b = blockIdx.z, h = blockIdx.y;
  int q0 = blockIdx.x * 64;
  int sm = t >> 2, sd = (t & 3) * 16;

  {  // stage Q transposed + scaled
    const float* src = Qb + ((long)(b * 2048 + q0 + sm)) * 1024 + h * 64 + sd;
    f32x4 v0 = *(const f32x4*)src;
    f32x4 v1 = *(const f32x4*)(src + 4);
    f32x4 v2 = *(const f32x4*)(src + 8);
    f32x4 v3 = *(const f32x4*)(src + 12);
#pragma unroll
    for (int i = 0; i < 4; i++) {
      Qt[sd + i][sm] = v0[i] * 0.125f;
      Qt[sd + 4 + i][sm] = v1[i] * 0.125f;
      Qt[sd + 8 + i][sm] = v2[i] * 0.125f;
      Qt[sd + 12 + i][sm] = v3[i] * 0.125f;
    }
  }

  float m_[4], l_[4], O[4][4];
#pragma unroll
  for (int i = 0; i < 4; i++) {
    m_[i] = -1e30f;
    l_[i] = 0.f;
#pragma unroll
    for (int j = 0; j < 4; j++) O[i][j] = 0.f;
  }

  for (int kb = 0; kb < 32; kb++) {
    __syncthreads();  // A: prior PV reads (and Qt staging at kb=0) complete
    int k0 = kb * 64;
    {  // stage K transposed, V direct
      const float* ks = KVb + ((long)(b * 2048 + k0 + sm)) * 2048 + h * 64 + sd;
      f32x4 k0v = *(const f32x4*)ks;
      f32x4 k1v = *(const f32x4*)(ks + 4);
      f32x4 k2v = *(const f32x4*)(ks + 8);
      f32x4 k3v = *(const f32x4*)(ks + 12);
#pragma unroll
      for (int i = 0; i < 4; i++) {
        KtPt[sd + i][sm] = k0v[i];
        KtPt[sd + 4 + i][sm] = k1v[i];
        KtPt[sd + 8 + i][sm] = k2v[i];
        KtPt[sd + 12 + i][sm] = k3v[i];
      }
      const float* vsrc = KVb + ((long)(b * 2048 + k0 + sm)) * 2048 + 1024 + h * 64 + sd;
      *(f32x4*)&Vs[sm][sd] = *(const f32x4*)vsrc;
      *(f32x4*)&Vs[sm][sd + 4] = *(const f32x4*)(vsrc + 4);
      *(f32x4*)&Vs[sm][sd + 8] = *(const f32x4*)(vsrc + 8);
      *(f32x4*)&Vs[sm][sd + 12] = *(const f32x4*)(vsrc + 12);
    }
    __syncthreads();  // B: staging complete

    // S = Q K^T
    float s[4][4] = {{0.f, 0.f, 0.f, 0.f}, {0.f, 0.f, 0.f, 0.f},
                     {0.f, 0.f, 0.f, 0.f}, {0.f, 0.f, 0.f, 0.f}};
#pragma unroll 8
    for (int d = 0; d < 64; d++) {
      f32x4 qv = *(const f32x4*)&Qt[d][ty * 4];
      f32x4 kv4 = *(const f32x4*)&KtPt[d][tx * 4];
#pragma unroll
      for (int i = 0; i < 4; i++)
#pragma unroll
        for (int j = 0; j < 4; j++) s[i][j] += qv[i] * kv4[j];
    }

    // online softmax (row max/sum over the 16 tx-lanes; same-wave contiguous)
    float mx[4], al[4], p[4][4], rs[4];
#pragma unroll
    for (int i = 0; i < 4; i++)
      mx[i] = fmaxf(fmaxf(s[i][0], s[i][1]), fmaxf(s[i][2], s[i][3]));
#pragma unroll
    for (int off = 1; off < 16; off <<= 1)
#pragma unroll
      for (int i = 0; i < 4; i++) mx[i] = fmaxf(mx[i], __shfl_xor(mx[i], off));
#pragma unroll
    for (int i = 0; i < 4; i++) {
      float mn = fmaxf(m_[i], mx[i]);
      al[i] = __expf(m_[i] - mn);
      m_[i] = mn;
      rs[i] = 0.f;
#pragma unroll
      for (int j = 0; j < 4; j++) {
        p[i][j] = __expf(s[i][j] - mn);
        rs[i] += p[i][j];
      }
    }
#pragma unroll
    for (int off = 1; off < 16; off <<= 1)
#pragma unroll
      for (int i = 0; i < 4; i++) rs[i] += __shfl_xor(rs[i], off);
#pragma unroll
    for (int i = 0; i < 4; i++) {
      l_[i] = l_[i] * al[i] + rs[i];
#pragma unroll
      for (int j = 0; j < 4; j++) O[i][j] *= al[i];
    }

    __syncthreads();  // B2: all QK^T reads of KtPt done before P^T overwrite

    // write P^T into KtPt, swizzled: row k=tx*4+j, q-group ty at col ((ty+tx)&15)*4
    int qoff = ((ty + tx) & 15) * 4;
#pragma unroll
    for (int j = 0; j < 4; j++) {
      f32x4 pj = {p[0][j], p[1][j], p[2][j], p[3][j]};
      *(f32x4*)&KtPt[tx * 4 + j][qoff] = pj;
    }
    __syncthreads();  // C: P^T visible

    // O += P V
#pragma unroll 8
    for (int k = 0; k < 64; k++) {
      f32x4 pk = *(const f32x4*)&KtPt[k][((ty + (k >> 2)) & 15) * 4];
      f32x4 vk = *(const f32x4*)&Vs[k][tx * 4];
#pragma unroll
      for (int i = 0; i < 4; i++)
#pragma unroll
        for (int j = 0; j < 4; j++) O[i][j] += pk[i] * vk[j];
    }
  }

#pragma unroll
  for (int i = 0; i < 4; i++) {
    float inv = 1.0f / l_[i];
    long obase = ((long)(b * 2048 + q0 + ty * 4 + i)) * 1024 + h * 64 + tx * 4;
#pragma unroll
    for (int j = 0; j < 4; j++) Out[obase + j] = O[i][j] * inv;
  }
}

// ---------------------------------------------------------------------------
// Workspace (MB, peak 76), liveness-checked:
//   [ 0,16): x_hi,x_lo      live: split -> kv-GEMM
//   [16,20): Wq_hi,Wq_lo    live: tsplit -> q-GEMM
//   [20,28): Wkv_hi,Wkv_lo  live: tsplit -> kv-GEMM
//   [28,44): q_raw fp32     live: q-GEMM -> attn (roped in place)
//   [44,76): kv_raw fp32    live: kv-GEMM -> attn (k roped in place)
//   [ 0,16): a_out fp32     live: attn -> a-split      (x dead)
//   [16,32): a_hi,a_lo      live: a-split -> out-GEMM  (Wq/Wkv/q_raw-head dead)
//   [32,36): Wo_hi,Wo_lo    live: tsplit -> out-GEMM   (q_raw dead)
// ---------------------------------------------------------------------------
extern "C" void kernel_launch(void* const* d_in, const int* in_sizes, int n_in,
                              void* d_out, int out_size, void* d_ws, size_t ws_size,
                              hipStream_t stream) {
  const float* x = (const float*)d_in[0];
  const float* Wq = (const float*)d_in[1];
  const float* Wkv = (const float*)d_in[2];
  const float* nqw = (const float*)d_in[3];
  const float* nkw = (const float*)d_in[4];
  const float* Wo = (const float*)d_in[5];
  const float* bo = (const float*)d_in[6];
  float* out = (float*)d_out;

  char* ws = (char*)d_ws;
  const long MB = 1l << 20;
  bf16* x_hi   = (bf16*)(ws);
  bf16* x_lo   = (bf16*)(ws + 8 * MB);
  bf16* Wq_hi  = (bf16*)(ws + 16 * MB);
  bf16* Wq_lo  = (bf16*)(ws + 18 * MB);
  bf16* Wkv_hi = (bf16*)(ws + 20 * MB);
  bf16* Wkv_lo = (bf16*)(ws + 24 * MB);
  float* q_raw  = (float*)(ws + 28 * MB);
  float* kv_raw = (float*)(ws + 44 * MB);
  float* a_out  = (float*)(ws);
  bf16* a_hi   = (bf16*)(ws + 16 * MB);
  bf16* a_lo   = (bf16*)(ws + 24 * MB);
  bf16* Wo_hi  = (bf16*)(ws + 32 * MB);
  bf16* Wo_lo  = (bf16*)(ws + 34 * MB);

  dim3 tb(32, 8);
  split_f32<<<4096, 256, 0, stream>>>(x, x_hi, x_lo, 4096l * 1024);
  tsplit<<<dim3(1024 / 32, 1024 / 32), tb, 0, stream>>>(Wq, Wq_hi, Wq_lo, 1024, 1024);
  tsplit<<<dim3(2048 / 32, 1024 / 32), tb, 0, stream>>>(Wkv, Wkv_hi, Wkv_lo, 1024, 2048);

  gemm_split<0><<<dim3(1024 / 64, 4096 / 64), 256, 0, stream>>>(
      x_hi, x_lo, Wq_hi, Wq_lo, nullptr, q_raw, 4096, 1024, 1024);
  gemm_split<0><<<dim3(2048 / 64, 4096 / 64), 256, 0, stream>>>(
      x_hi, x_lo, Wkv_hi, Wkv_lo, nullptr, kv_raw, 4096, 2048, 1024);

  normrope_kernel<<<dim3(4096, 2), 256, 0, stream>>>(q_raw, kv_raw, nqw, nkw);

  attn_kernel<<<dim3(32, 16, 2), 256, 0, stream>>>(q_raw, kv_raw, a_out);

  split_f32<<<4096, 256, 0, stream>>>(a_out, a_hi, a_lo, 4096l * 1024);
  tsplit<<<dim3(1024 / 32, 1024 / 32), tb, 0, stream>>>(Wo, Wo_hi, Wo_lo, 1024, 1024);

  gemm_split<1><<<dim3(1024 / 64, 4096 / 64), 256, 0, stream>>>(
      a_hi, a_lo, Wo_hi, Wo_lo, bo, out, 4096, 1024, 1024);
}

// Round 4
// 439.188 us; speedup vs baseline: 1.7810x; 1.7810x over previous
//
#include <hip/hip_runtime.h>

typedef __bf16 bf16;
typedef __bf16 bf16x4 __attribute__((ext_vector_type(4)));
typedef __bf16 bf16x8 __attribute__((ext_vector_type(8)));
typedef float  f32x4  __attribute__((ext_vector_type(4)));

// ---------------------------------------------------------------------------
// Split fp32 -> bf16 hi + bf16 lo
// ---------------------------------------------------------------------------
__global__ __launch_bounds__(256) void split_f32(const float* __restrict__ in,
                                                 bf16* __restrict__ hi,
                                                 bf16* __restrict__ lo, long n4) {
  long i = ((long)blockIdx.x * 256 + threadIdx.x) * 4;
  if (i >= n4) return;
  f32x4 v = *(const f32x4*)(in + i);
  bf16x4 h, l;
#pragma unroll
  for (int j = 0; j < 4; j++) {
    bf16 hh = (bf16)v[j];
    h[j] = hh;
    l[j] = (bf16)(v[j] - (float)hh);
  }
  *(bf16x4*)(hi + i) = h;
  *(bf16x4*)(lo + i) = l;
}

// ---------------------------------------------------------------------------
// Transpose + split: float in[R][C] -> bf16 hi[C][R], lo[C][R].  block (32,8)
// ---------------------------------------------------------------------------
__global__ __launch_bounds__(256) void tsplit(const float* __restrict__ in,
                                              bf16* __restrict__ hi,
                                              bf16* __restrict__ lo, int R, int C) {
  __shared__ float tile[32][33];
  int tx = threadIdx.x, ty = threadIdx.y;
  int c = blockIdx.x * 32 + tx;
#pragma unroll
  for (int i = 0; i < 4; i++) {
    int r = blockIdx.y * 32 + ty + i * 8;
    tile[ty + i * 8][tx] = in[(long)r * C + c];
  }
  __syncthreads();
  int c2 = blockIdx.y * 32 + tx;
#pragma unroll
  for (int i = 0; i < 4; i++) {
    int r2 = blockIdx.x * 32 + ty + i * 8;
    float v = tile[tx][ty + i * 8];
    bf16 h = (bf16)v;
    hi[(long)r2 * R + c2] = h;
    lo[(long)r2 * R + c2] = (bf16)(v - (float)h);
  }
}

// ---------------------------------------------------------------------------
// V pre-transpose: vt[b][h][d][n] (bf16) = KV[b*2048+n][1024 + h*64 + d]
// grid (64 n-tiles, 2 d-tiles, 32 b*h), block (32,8)
// ---------------------------------------------------------------------------
__global__ __launch_bounds__(256) void vtrans(const float* __restrict__ kv,
                                              bf16* __restrict__ vt) {
  __shared__ float tile[32][33];
  int tx = threadIdx.x, ty = threadIdx.y;
  int n0 = blockIdx.x * 32, d0 = blockIdx.y * 32, bh = blockIdx.z;
  int b = bh >> 4, h = bh & 15;
#pragma unroll
  for (int i = 0; i < 4; i++) {
    int n = n0 + ty + i * 8;
    tile[ty + i * 8][tx] = kv[(long)(b * 2048 + n) * 2048 + 1024 + h * 64 + d0 + tx];
  }
  __syncthreads();
#pragma unroll
  for (int i = 0; i < 4; i++) {
    int d = d0 + ty + i * 8;
    vt[((long)(bh * 64 + d)) * 2048 + n0 + tx] = (bf16)tile[tx][ty + i * 8];
  }
}

// ---------------------------------------------------------------------------
// Split-precision GEMM: C[M,N] = (Ah+Al)[M,K] @ (Bh+Bl)[N,K]^T  (fp32 out)
// 64x64 tile, BK=32, 4 waves, 2x2 MFMA 16x16x32, 3 terms: hh + lh + hl.
// ---------------------------------------------------------------------------
template <int BIAS>
__global__ __launch_bounds__(256) void gemm_split(const bf16* __restrict__ Ah_g,
                                                  const bf16* __restrict__ Al_g,
                                                  const bf16* __restrict__ Bh_g,
                                                  const bf16* __restrict__ Bl_g,
                                                  const float* __restrict__ bias,
                                                  float* __restrict__ C,
                                                  int M, int N, int K) {
  __shared__ __align__(16) bf16 Ah[64][40], Al[64][40], Bh[64][40], Bl[64][40];
  int t = threadIdx.x;
  int lane = t & 63, wave = t >> 6;
  int wm = wave >> 1, wn = wave & 1;
  int m0 = blockIdx.y * 64, n0 = blockIdx.x * 64;
  int srow = t >> 2, scol = (t & 3) * 8;
  int q = lane >> 4, r = lane & 15;

  long aoff = (long)(m0 + srow) * K + scol;
  long boff = (long)(n0 + srow) * K + scol;

  f32x4 acc00 = {0.f, 0.f, 0.f, 0.f}, acc01 = acc00, acc10 = acc00, acc11 = acc00;

  for (int k0 = 0; k0 < K; k0 += 32) {
    *(bf16x8*)&Ah[srow][scol] = *(const bf16x8*)(Ah_g + aoff + k0);
    *(bf16x8*)&Al[srow][scol] = *(const bf16x8*)(Al_g + aoff + k0);
    *(bf16x8*)&Bh[srow][scol] = *(const bf16x8*)(Bh_g + boff + k0);
    *(bf16x8*)&Bl[srow][scol] = *(const bf16x8*)(Bl_g + boff + k0);
    __syncthreads();
    bf16x8 a0h = *(const bf16x8*)&Ah[wm * 32 + r][q * 8];
    bf16x8 a1h = *(const bf16x8*)&Ah[wm * 32 + 16 + r][q * 8];
    bf16x8 a0l = *(const bf16x8*)&Al[wm * 32 + r][q * 8];
    bf16x8 a1l = *(const bf16x8*)&Al[wm * 32 + 16 + r][q * 8];
    bf16x8 b0h = *(const bf16x8*)&Bh[wn * 32 + r][q * 8];
    bf16x8 b1h = *(const bf16x8*)&Bh[wn * 32 + 16 + r][q * 8];
    bf16x8 b0l = *(const bf16x8*)&Bl[wn * 32 + r][q * 8];
    bf16x8 b1l = *(const bf16x8*)&Bl[wn * 32 + 16 + r][q * 8];
    acc00 = __builtin_amdgcn_mfma_f32_16x16x32_bf16(a0h, b0h, acc00, 0, 0, 0);
    acc00 = __builtin_amdgcn_mfma_f32_16x16x32_bf16(a0l, b0h, acc00, 0, 0, 0);
    acc00 = __builtin_amdgcn_mfma_f32_16x16x32_bf16(a0h, b0l, acc00, 0, 0, 0);
    acc01 = __builtin_amdgcn_mfma_f32_16x16x32_bf16(a0h, b1h, acc01, 0, 0, 0);
    acc01 = __builtin_amdgcn_mfma_f32_16x16x32_bf16(a0l, b1h, acc01, 0, 0, 0);
    acc01 = __builtin_amdgcn_mfma_f32_16x16x32_bf16(a0h, b1l, acc01, 0, 0, 0);
    acc10 = __builtin_amdgcn_mfma_f32_16x16x32_bf16(a1h, b0h, acc10, 0, 0, 0);
    acc10 = __builtin_amdgcn_mfma_f32_16x16x32_bf16(a1l, b0h, acc10, 0, 0, 0);
    acc10 = __builtin_amdgcn_mfma_f32_16x16x32_bf16(a1h, b0l, acc10, 0, 0, 0);
    acc11 = __builtin_amdgcn_mfma_f32_16x16x32_bf16(a1h, b1h, acc11, 0, 0, 0);
    acc11 = __builtin_amdgcn_mfma_f32_16x16x32_bf16(a1l, b1h, acc11, 0, 0, 0);
    acc11 = __builtin_amdgcn_mfma_f32_16x16x32_bf16(a1h, b1l, acc11, 0, 0, 0);
    __syncthreads();
  }

  int rbase = m0 + wm * 32 + q * 4;
  int cbase = n0 + wn * 32 + r;
  auto emit = [&](f32x4 v, int rb, int col) {
#pragma unroll
    for (int i = 0; i < 4; i++) {
      float val = v[i];
      if (BIAS) val += bias[col];
      C[(long)(rb + i) * N + col] = val;
    }
  };
  emit(acc00, rbase, cbase);
  emit(acc01, rbase, cbase + 16);
  emit(acc10, rbase + 16, cbase);
  emit(acc11, rbase + 16, cbase + 16);
}

// ---------------------------------------------------------------------------
// RMSNorm (inner=1024) + RoPE, output split bf16 hi/lo (post-rope value *scale).
// grid 4096, block 256. src row stride = src_stride; out row stride = 1024.
// ---------------------------------------------------------------------------
__global__ __launch_bounds__(256) void normrope_split(const float* __restrict__ src,
                                                      int src_stride,
                                                      const float* __restrict__ w,
                                                      bf16* __restrict__ oh,
                                                      bf16* __restrict__ ol,
                                                      float scale) {
  int row = blockIdx.x;
  const float* sp = src + (long)row * src_stride;
  int t = threadIdx.x;
  int j0 = t * 4;

  f32x4 xv = *(const f32x4*)(sp + j0);
  float ss = xv[0] * xv[0] + xv[1] * xv[1] + xv[2] * xv[2] + xv[3] * xv[3];
#pragma unroll
  for (int off = 32; off > 0; off >>= 1) ss += __shfl_down(ss, off);
  __shared__ float red[4];
  if ((t & 63) == 0) red[t >> 6] = ss;
  __syncthreads();
  float total = red[0] + red[1] + red[2] + red[3];
  float nsc = rsqrtf(total * (1.0f / 1024.0f) + 1e-6f);

  int n = row & 2047;
#pragma unroll
  for (int pp = 0; pp < 2; pp++) {
    int j = j0 + 2 * pp;
    int ii = (j & 63) >> 1;
    float theta = __expf((float)ii * (-9.210340371976184f / 32.0f));
    float ang = (float)n * theta;
    float sn, cs;
    __sincosf(ang, &sn, &cs);
    float a0 = xv[2 * pp] * nsc * w[j];
    float a1 = xv[2 * pp + 1] * nsc * w[j + 1];
    float r0 = (cs * a0 - sn * a1) * scale;
    float r1 = (sn * a0 + cs * a1) * scale;
    bf16 h0 = (bf16)r0, h1 = (bf16)r1;
    long o = (long)row * 1024 + j;
    oh[o] = h0;
    ol[o] = (bf16)(r0 - (float)h0);
    oh[o + 1] = h1;
    ol[o + 1] = (bf16)(r1 - (float)h1);
  }
}

// ---------------------------------------------------------------------------
// MFMA flash attention. Block = (64 q-rows, head h, batch b); 4 waves x 16 rows.
// QK^T: 3-term split (qh/ql x kh/kl).  PV: 2-term (Ph+Pl) x Vh.
// P transform C-layout -> A-layout via per-wave fp32 LDS round trip.
// Emits attention output pre-split (ah, al bf16) for the out-projection GEMM.
// ---------------------------------------------------------------------------
__global__ __launch_bounds__(256) void attn_mfma(const bf16* __restrict__ qh,
                                                 const bf16* __restrict__ ql,
                                                 const bf16* __restrict__ kh,
                                                 const bf16* __restrict__ kl,
                                                 const bf16* __restrict__ vt,
                                                 bf16* __restrict__ ah,
                                                 bf16* __restrict__ al) {
  __shared__ __align__(16) bf16 Kh[64][72], Kl[64][72], Vt[64][72];
  __shared__ __align__(16) float Pb[4][16][68];

  int t = threadIdx.x;
  int lane = t & 63, w = t >> 6;
  int m = lane & 15, qq = lane >> 4;
  int b = blockIdx.z, h = blockIdx.y, q0 = blockIdx.x * 64;

  // Q A-frags from global (held in registers all kernel)
  long qrow = (long)b * 2048 + q0 + w * 16 + m;
  const bf16* qbh = qh + qrow * 1024 + h * 64 + qq * 8;
  const bf16* qbl = ql + qrow * 1024 + h * 64 + qq * 8;
  bf16x8 qfh0 = *(const bf16x8*)qbh;
  bf16x8 qfh1 = *(const bf16x8*)(qbh + 32);
  bf16x8 qfl0 = *(const bf16x8*)qbl;
  bf16x8 qfl1 = *(const bf16x8*)(qbl + 32);

  f32x4 O[4];
  float m_[4], l_[4];
#pragma unroll
  for (int i = 0; i < 4; i++) {
    O[i] = f32x4{0.f, 0.f, 0.f, 0.f};
    m_[i] = -1e30f;
    l_[i] = 0.f;
  }

  int srow = t >> 2, scol = (t & 3) * 16;
  const bf16* khb = kh + ((long)b * 2048 + srow) * 1024 + h * 64 + scol;
  const bf16* klb = kl + ((long)b * 2048 + srow) * 1024 + h * 64 + scol;
  const bf16* vtb = vt + ((long)((b * 16 + h) * 64 + srow)) * 2048 + scol;

  for (int kb = 0; kb < 32; kb++) {
    __syncthreads();  // all waves done with previous K/V tiles
    long ko = (long)kb * 64 * 1024;
    *(bf16x8*)&Kh[srow][scol] = *(const bf16x8*)(khb + ko);
    *(bf16x8*)&Kh[srow][scol + 8] = *(const bf16x8*)(khb + ko + 8);
    *(bf16x8*)&Kl[srow][scol] = *(const bf16x8*)(klb + ko);
    *(bf16x8*)&Kl[srow][scol + 8] = *(const bf16x8*)(klb + ko + 8);
    *(bf16x8*)&Vt[srow][scol] = *(const bf16x8*)(vtb + kb * 64);
    *(bf16x8*)&Vt[srow][scol + 8] = *(const bf16x8*)(vtb + kb * 64 + 8);
    __syncthreads();  // staging visible

    // S = Q K^T  (16q x 64k per wave)
    f32x4 s[4];
#pragma unroll
    for (int nt = 0; nt < 4; nt++) s[nt] = f32x4{0.f, 0.f, 0.f, 0.f};
#pragma unroll
    for (int ks = 0; ks < 2; ks++) {
      bf16x8 qfh = ks ? qfh1 : qfh0;
      bf16x8 qfl = ks ? qfl1 : qfl0;
#pragma unroll
      for (int nt = 0; nt < 4; nt++) {
        bf16x8 kfh = *(const bf16x8*)&Kh[nt * 16 + m][ks * 32 + qq * 8];
        bf16x8 kfl = *(const bf16x8*)&Kl[nt * 16 + m][ks * 32 + qq * 8];
        s[nt] = __builtin_amdgcn_mfma_f32_16x16x32_bf16(qfh, kfh, s[nt], 0, 0, 0);
        s[nt] = __builtin_amdgcn_mfma_f32_16x16x32_bf16(qfl, kfh, s[nt], 0, 0, 0);
        s[nt] = __builtin_amdgcn_mfma_f32_16x16x32_bf16(qfh, kfl, s[nt], 0, 0, 0);
      }
    }

    // online softmax; C-layout: col(key within tile)=m lane group, row=qq*4+i
    float mx[4];
#pragma unroll
    for (int i = 0; i < 4; i++)
      mx[i] = fmaxf(fmaxf(s[0][i], s[1][i]), fmaxf(s[2][i], s[3][i]));
#pragma unroll
    for (int off = 1; off < 16; off <<= 1)
#pragma unroll
      for (int i = 0; i < 4; i++) mx[i] = fmaxf(mx[i], __shfl_xor(mx[i], off));

    float al_[4], rs[4];
#pragma unroll
    for (int i = 0; i < 4; i++) {
      float mn = fmaxf(m_[i], mx[i]);
      al_[i] = __expf(m_[i] - mn);
      m_[i] = mn;
    }
    float p[4][4];  // [nt][i]
#pragma unroll
    for (int i = 0; i < 4; i++) {
      rs[i] = 0.f;
#pragma unroll
      for (int nt = 0; nt < 4; nt++) {
        p[nt][i] = __expf(s[nt][i] - m_[i]);
        rs[i] += p[nt][i];
      }
    }
#pragma unroll
    for (int off = 1; off < 16; off <<= 1)
#pragma unroll
      for (int i = 0; i < 4; i++) rs[i] += __shfl_xor(rs[i], off);
#pragma unroll
    for (int i = 0; i < 4; i++) {
      l_[i] = l_[i] * al_[i] + rs[i];
#pragma unroll
      for (int nt = 0; nt < 4; nt++) O[nt][i] *= al_[i];
    }

    // P: C-layout -> A-layout via per-wave LDS buffer (wave-private: no barrier)
#pragma unroll
    for (int nt = 0; nt < 4; nt++)
#pragma unroll
      for (int i = 0; i < 4; i++) Pb[w][qq * 4 + i][nt * 16 + m] = p[nt][i];

#pragma unroll
    for (int ks = 0; ks < 2; ks++) {
      f32x4 pa = *(const f32x4*)&Pb[w][m][ks * 32 + qq * 8];
      f32x4 pc = *(const f32x4*)&Pb[w][m][ks * 32 + qq * 8 + 4];
      bf16x8 pfh, pfl;
#pragma unroll
      for (int j = 0; j < 4; j++) {
        bf16 h0 = (bf16)pa[j];
        pfh[j] = h0;
        pfl[j] = (bf16)(pa[j] - (float)h0);
        bf16 h1 = (bf16)pc[j];
        pfh[4 + j] = h1;
        pfl[4 + j] = (bf16)(pc[j] - (float)h1);
      }
#pragma unroll
      for (int nt = 0; nt < 4; nt++) {
        bf16x8 vf = *(const bf16x8*)&Vt[nt * 16 + m][ks * 32 + qq * 8];
        O[nt] = __builtin_amdgcn_mfma_f32_16x16x32_bf16(pfh, vf, O[nt], 0, 0, 0);
        O[nt] = __builtin_amdgcn_mfma_f32_16x16x32_bf16(pfl, vf, O[nt], 0, 0, 0);
      }
    }
  }

  // epilogue: normalize + split-store (C-layout: row=qq*4+i, col=nt*16+m)
  float inv[4];
#pragma unroll
  for (int i = 0; i < 4; i++) inv[i] = 1.0f / l_[i];
#pragma unroll
  for (int nt = 0; nt < 4; nt++)
#pragma unroll
    for (int i = 0; i < 4; i++) {
      float val = O[nt][i] * inv[i];
      long orow = (long)b * 2048 + q0 + w * 16 + qq * 4 + i;
      long o = orow * 1024 + h * 64 + nt * 16 + m;
      bf16 hh = (bf16)val;
      ah[o] = hh;
      al[o] = (bf16)(val - (float)hh);
    }
}

// ---------------------------------------------------------------------------
// Workspace (MB, peak 60; 76 known-safe), liveness:
//   [ 0,16): x_hi,x_lo    split -> kv-GEMM
//   [16,20): Wq h/l       tsplit -> q-GEMM
//   [20,28): Wkv h/l      tsplit -> kv-GEMM
//   [28,44): q_raw        q-GEMM -> normrope_q
//   [44,76): kv_raw       kv-GEMM -> normrope_k (k half) / vtrans (v half)
//   [ 0,16): qh,ql        normrope_q -> attn      (x dead)
//   [16,32): kh,kl        normrope_k -> attn      (Wq/Wkv/q_raw-head dead)
//   [32,40): vt           vtrans -> attn          (q_raw dead)
//   [40,56): ah,al        attn -> out-GEMM        (q_raw tail/kv_raw dead)
//   [56,60): Wo h/l       tsplit -> out-GEMM      (kv_raw dead)
// ---------------------------------------------------------------------------
extern "C" void kernel_launch(void* const* d_in, const int* in_sizes, int n_in,
                              void* d_out, int out_size, void* d_ws, size_t ws_size,
                              hipStream_t stream) {
  const float* x = (const float*)d_in[0];
  const float* Wq = (const float*)d_in[1];
  const float* Wkv = (const float*)d_in[2];
  const float* nqw = (const float*)d_in[3];
  const float* nkw = (const float*)d_in[4];
  const float* Wo = (const float*)d_in[5];
  const float* bo = (const float*)d_in[6];
  float* out = (float*)d_out;

  char* ws = (char*)d_ws;
  const long MB = 1l << 20;
  bf16* x_hi   = (bf16*)(ws);
  bf16* x_lo   = (bf16*)(ws + 8 * MB);
  bf16* Wq_hi  = (bf16*)(ws + 16 * MB);
  bf16* Wq_lo  = (bf16*)(ws + 18 * MB);
  bf16* Wkv_hi = (bf16*)(ws + 20 * MB);
  bf16* Wkv_lo = (bf16*)(ws + 24 * MB);
  float* q_raw  = (float*)(ws + 28 * MB);
  float* kv_raw = (float*)(ws + 44 * MB);
  bf16* qh = (bf16*)(ws);
  bf16* ql = (bf16*)(ws + 8 * MB);
  bf16* kh = (bf16*)(ws + 16 * MB);
  bf16* kl = (bf16*)(ws + 24 * MB);
  bf16* vt = (bf16*)(ws + 32 * MB);
  bf16* ah = (bf16*)(ws + 40 * MB);
  bf16* al = (bf16*)(ws + 48 * MB);
  bf16* Wo_hi = (bf16*)(ws + 56 * MB);
  bf16* Wo_lo = (bf16*)(ws + 58 * MB);

  dim3 tb(32, 8);
  split_f32<<<4096, 256, 0, stream>>>(x, x_hi, x_lo, 4096l * 1024);
  tsplit<<<dim3(1024 / 32, 1024 / 32), tb, 0, stream>>>(Wq, Wq_hi, Wq_lo, 1024, 1024);
  tsplit<<<dim3(2048 / 32, 1024 / 32), tb, 0, stream>>>(Wkv, Wkv_hi, Wkv_lo, 1024, 2048);

  gemm_split<0><<<dim3(1024 / 64, 4096 / 64), 256, 0, stream>>>(
      x_hi, x_lo, Wq_hi, Wq_lo, nullptr, q_raw, 4096, 1024, 1024);
  gemm_split<0><<<dim3(2048 / 64, 4096 / 64), 256, 0, stream>>>(
      x_hi, x_lo, Wkv_hi, Wkv_lo, nullptr, kv_raw, 4096, 2048, 1024);

  // q: scale 1/8 folded pre-split; k: unscaled
  normrope_split<<<4096, 256, 0, stream>>>(q_raw, 1024, nqw, qh, ql, 0.125f);
  normrope_split<<<4096, 256, 0, stream>>>(kv_raw, 2048, nkw, kh, kl, 1.0f);

  vtrans<<<dim3(64, 2, 32), tb, 0, stream>>>(kv_raw, vt);

  attn_mfma<<<dim3(32, 16, 2), 256, 0, stream>>>(qh, ql, kh, kl, vt, ah, al);

  tsplit<<<dim3(1024 / 32, 1024 / 32), tb, 0, stream>>>(Wo, Wo_hi, Wo_lo, 1024, 1024);

  gemm_split<1><<<dim3(1024 / 64, 4096 / 64), 256, 0, stream>>>(
      ah, al, Wo_hi, Wo_lo, bo, out, 4096, 1024, 1024);
}